// Round 3
// baseline (1802.978 us; speedup 1.0000x reference)
//
#include <hip/hip_runtime.h>
#include <hip/hip_bf16.h>
#include <math.h>

#define B_   4096
#define T_   16
#define F_   256
#define U_   512
#define M_   8
#define K_   768    // F+U
#define NRS  4096   // U*M
#define NC   8192   // combined R|S output cols
#define LNT  1.1512925f  // 0.5*ln(10)

typedef __bf16 bf16_t;
typedef bf16_t bf16x8 __attribute__((ext_vector_type(8)));
typedef bf16_t bf16x4 __attribute__((ext_vector_type(4)));
typedef float  f32x4  __attribute__((ext_vector_type(4)));

__device__ inline void gl_lds16(const void* g, void* lds) {
    __builtin_amdgcn_global_load_lds(
        (const __attribute__((address_space(1))) unsigned int*)g,
        (__attribute__((address_space(3))) unsigned int*)lds, 16, 0, 0);
}

#define VMCNT(n) asm volatile("s_waitcnt vmcnt(" #n ")" ::: "memory")
#define LGKM0()  asm volatile("s_waitcnt lgkmcnt(0)" ::: "memory")
#define BAR()    __builtin_amdgcn_s_barrier()

// ---------------------------------------------------------------------------
// Stage one 256x32 bf16 slot (16KB): 512 thr x 2 x 16B. LDS dest LINEAR
// (global_load_lds requirement); T2 swizzle applied by inverse-permuting the
// per-lane GLOBAL source column; ds_read applies the same XOR (both-sides).
// k0 is a multiple of 32 so a slot never straddles the xt|hprev boundary.
// ---------------------------------------------------------------------------
__device__ inline void stageA(bf16_t* dst, const bf16_t* xt, const bf16_t* hp,
                              int m0, int k0, int tid) {
    const int r = tid >> 2;
    const int c = ((tid & 3) ^ ((tid >> 3) & 3)) * 8;
    const bf16_t *s0, *s1;
    if (k0 < F_) {
        s0 = xt + (size_t)(m0 + r) * F_ + k0 + c;
        s1 = xt + (size_t)(m0 + r + 128) * F_ + k0 + c;
    } else {
        s0 = hp + (size_t)(m0 + r) * U_ + (k0 - F_) + c;
        s1 = hp + (size_t)(m0 + r + 128) * U_ + (k0 - F_) + c;
    }
    gl_lds16(s0, (char*)dst + tid * 16);
    gl_lds16(s1, (char*)dst + (tid + 512) * 16);
}

__device__ inline void stageB(bf16_t* dst, const bf16_t* Bt, int n0, int k0, int tid) {
    const int r = tid >> 2;
    const int c = ((tid & 3) ^ ((tid >> 3) & 3)) * 8;
    gl_lds16(Bt + (size_t)(n0 + r) * K_ + k0 + c,       (char*)dst + tid * 16);
    gl_lds16(Bt + (size_t)(n0 + r + 128) * K_ + k0 + c, (char*)dst + (tid + 512) * 16);
}

__device__ inline void ds_read4(const bf16_t* base, bf16x8 (&v)[4]) {
    v[0] = *(const bf16x8*)(base);
    v[1] = *(const bf16x8*)(base + 512);
    v[2] = *(const bf16x8*)(base + 1024);
    v[3] = *(const bf16x8*)(base + 1536);
}

template <int H>
__device__ inline void mfma16(f32x4 (&acc)[8][4], const bf16x8 (&a)[4],
                              const bf16x8 (&b)[4]) {
    __builtin_amdgcn_s_setprio(1);
#pragma unroll
    for (int i = 0; i < 4; ++i)
#pragma unroll
        for (int j = 0; j < 4; ++j)
            acc[H * 4 + i][j] = __builtin_amdgcn_mfma_f32_16x16x32_bf16(
                a[i], b[j], acc[H * 4 + i][j], 0, 0, 0);
    __builtin_amdgcn_s_setprio(0);
}

// ---------------------------------------------------------------------------
// Combined R|S GEMM, 256x256 tile, 8 waves (2Mx4N), per-wave 128x64.
// BK=32, LDS 64 KiB (2-slot parity dbuf per matrix) -> TWO blocks/CU
// (VGPR 120 <= 128), so cross-block TLP fills every latency bubble that the
// 1-block/CU R1/R2 structure exposed. ONE barrier per K-tile:
//   tile t (parity p=t&1): [stage A,B(t+1) -> p^1] ; dsA-mh0[p]+dsB[p];
//   lgkm0; MFMA h0; dsA-mh1[p]; lgkm0; MFMA h1; vmcnt(0); BAR.
// Hazards: reads hit parity p only, stages hit p^1 only (disjoint); all
// readers of p^1 (tile t-1) drained their lgkm before reaching tile t-1's
// end-BAR, which precedes tile t's stages. Per-wave vmcnt(0) sits after the
// MFMA cluster (max in-tile cover); end-BAR then publishes slot t+1 complete
// to all waves before any ph1(t+1) read.
// ---------------------------------------------------------------------------
__global__ __launch_bounds__(512, 2) void gemm_rs_p2(
    const bf16_t* __restrict__ xt,     // [B_][F_]
    const bf16_t* __restrict__ hprev,  // [B_][U_]
    const bf16_t* __restrict__ Bt,     // WrsT [NC][K_] (perm)
    const float*  __restrict__ biasP,  // [NC] (perm)
    const bf16_t* __restrict__ hhat,   // [B_][NRS]
    bf16_t* __restrict__ rh,           // [B_][U_]
    bf16_t* __restrict__ sbuf)         // [B_][NRS]
{
    __shared__ bf16_t Asl[2][256 * 32];   // 32 KiB
    __shared__ bf16_t Bsl[2][256 * 32];   // 32 KiB

    const int tid  = threadIdx.x;
    const int lane = tid & 63;
    const int wave = tid >> 6;

    // Bijective XCD swizzle: XCD c owns a 4m x 16n rectangle (verified R2:
    // FETCH 118->53.5 MB, near-minimal).
    const int lin = blockIdx.y * 16 + blockIdx.x;
    const int xcd = lin & 7, q = lin >> 3;
    const int m0 = ((xcd >> 1) * 4 + (q & 3)) * 256;
    const int n0 = ((xcd & 1) * 16 + (q >> 2)) * 256;

    const int wm = wave >> 2;          // 0..1
    const int wn = wave & 3;           // 0..3
    const int lr = lane & 15;
    const int kq = lane >> 4;
    // T2 read-side swizzle: 16B-slot = kq ^ ((row>>1)&3); row=16a+lr -> lane-uniform.
    const int cr = (kq ^ ((lr >> 1) & 3)) * 8;

    const int aoff0 = (wm * 128 + lr) * 32 + cr;        // M-half 0
    const int aoff1 = (wm * 128 + 64 + lr) * 32 + cr;   // M-half 1
    const int boff  = (wn * 64 + lr) * 32 + cr;

    f32x4 acc[8][4] = {};
    bf16x8 a[4], b[4];

    // Prologue: slot 0 staged, drained.
    stageA(&Asl[0][0], xt, hprev, m0, 0, tid);
    stageB(&Bsl[0][0], Bt, n0, 0, tid);
    VMCNT(0);
    BAR();

#define TILE(T, SFLAG)                                                        \
  {                                                                           \
    const int p_ = (T) & 1, pn_ = p_ ^ 1;                                     \
    if (SFLAG) {                                                              \
      stageA(&Asl[pn_][0], xt, hprev, m0, ((T) + 1) * 32, tid);               \
      stageB(&Bsl[pn_][0], Bt, n0, ((T) + 1) * 32, tid);                      \
    }                                                                         \
    ds_read4(&Asl[p_][0] + aoff0, a);                                         \
    ds_read4(&Bsl[p_][0] + boff, b);                                          \
    LGKM0();                                                                  \
    mfma16<0>(acc, a, b);                                                     \
    ds_read4(&Asl[p_][0] + aoff1, a);                                         \
    LGKM0();                                                                  \
    mfma16<1>(acc, a, b);                                                     \
    VMCNT(0);                                                                 \
    BAR();                                                                    \
  }

    for (int tt = 0; tt < 22; tt += 2) { TILE(tt, 1); TILE(tt + 1, 1); }
    TILE(22, 1);
    TILE(23, 0);
#undef TILE

    // ------------------- fused softmax epilogue (unchanged math) -----------
    const int nb  = n0 + wn * 64;
    const int u3  = lane & 7;
    const int m0v = ((lane >> 3) & 1) * 4;
    const bool is_r = nb < NRS;

    float bj[4];
#pragma unroll
    for (int j = 0; j < 4; ++j) bj[j] = biasP[nb + j * 16 + lr];

#pragma unroll
    for (int mi = 0; mi < 8; ++mi) {
        const int rowb = m0 + wm * 128 + mi * 16 + kq * 4;
#pragma unroll
        for (int r = 0; r < 4; ++r) {
            const int row = rowb + r;
            float e[4], sum = 0.f;
#pragma unroll
            for (int j = 0; j < 4; ++j) {
                float v = acc[mi][j][r] + bj[j];
                float d = v - (float)(m0v + j) * LNT;
                e[j] = __expf(-d * d);
                sum += e[j];
            }
            sum += __shfl_xor(sum, 8, 64);
            const float inv = 1.0f / sum;
            if (is_r) {
                bf16x4 h4 = *(const bf16x4*)(hhat + (size_t)row * NRS + nb + u3 * 8 + m0v);
                float rhv = 0.f;
#pragma unroll
                for (int j = 0; j < 4; ++j) rhv += e[j] * inv * (float)h4[j];
                rhv += __shfl_xor(rhv, 8, 64);
                if ((lane & 8) == 0)
                    rh[(size_t)row * U_ + (nb >> 3) + u3] = (bf16_t)rhv;
            } else {
                bf16x4 pv;
#pragma unroll
                for (int j = 0; j < 4; ++j) pv[j] = (bf16_t)(e[j] * inv);
                *(bf16x4*)(sbuf + (size_t)row * NRS + (nb - NRS) + u3 * 8 + m0v) = pv;
            }
        }
    }
}

// ---------------------------------------------------------------------------
// q GEMM (64x64 tiles, grid 64x8=512) + fused state update; writes this
// step's hidden into hall slice t (persistent; next rs reads it as hprev).
// ---------------------------------------------------------------------------
__global__ __launch_bounds__(256) void gemm_q_up(
    const bf16_t* __restrict__ xt,     // [B_][F_]
    const bf16_t* __restrict__ rh,     // [B_][U_]
    const bf16_t* __restrict__ Bq,     // WqT [U_][K_]
    const float*  __restrict__ bq,
    const bf16_t* __restrict__ sbuf,
    bf16_t* __restrict__ hhat,
    bf16_t* __restrict__ hnext)        // hall slice t: [B_][U_]
{
    __shared__ bf16_t Al[2][64 * 32];
    __shared__ bf16_t Bl[2][64 * 32];

    const int tid  = threadIdx.x;
    const int lane = tid & 63;
    const int wave = tid >> 6;
    const int m0 = blockIdx.x * 64;
    const int n0 = blockIdx.y * 64;
    const int wm = (wave & 1) * 32;
    const int wn = (wave >> 1) * 32;
    const int lr = lane & 15;
    const int kq = lane >> 4;

    f32x4 acc[2][2] = {};

    const int rA = tid >> 2;
    const int kc = (tid & 3) * 8;

    for (int kk = 0; kk < K_; kk += 64) {
        const bf16_t* arow;
        int cbase;
        if (kk < F_) { arow = xt + (size_t)(m0 + rA) * F_; cbase = kk; }
        else         { arow = rh + (size_t)(m0 + rA) * U_; cbase = kk - F_; }

        __syncthreads();
        gl_lds16(arow + cbase + kc,      (char*)&Al[0][0] + tid * 16);
        gl_lds16(arow + cbase + 32 + kc, (char*)&Al[1][0] + tid * 16);
        gl_lds16(Bq + (size_t)(n0 + rA) * K_ + kk + kc,      (char*)&Bl[0][0] + tid * 16);
        gl_lds16(Bq + (size_t)(n0 + rA) * K_ + kk + 32 + kc, (char*)&Bl[1][0] + tid * 16);
        __syncthreads();

#pragma unroll
        for (int s = 0; s < 2; s++) {
            bf16x8 af[2], bfr[2];
#pragma unroll
            for (int i = 0; i < 2; i++)
                af[i] = *(const bf16x8*)(&Al[s][0] + (wm + i * 16 + lr) * 32 + kq * 8);
#pragma unroll
            for (int i = 0; i < 2; i++)
                bfr[i] = *(const bf16x8*)(&Bl[s][0] + (wn + i * 16 + lr) * 32 + kq * 8);
#pragma unroll
            for (int i = 0; i < 2; i++)
#pragma unroll
                for (int j = 0; j < 2; j++)
                    acc[i][j] = __builtin_amdgcn_mfma_f32_16x16x32_bf16(
                        af[i], bfr[j], acc[i][j], 0, 0, 0);
        }
    }

    const float DEC[8] = {0.0f, 0.9658531f, 0.9827783f, 0.9884856f,
                          0.9913518f, 0.9930754f, 0.9942261f, 0.9950489f};

#pragma unroll
    for (int i = 0; i < 2; i++) {
        const int rowb = m0 + wm + i * 16 + kq * 4;
#pragma unroll
        for (int j = 0; j < 2; j++) {
            const int u = n0 + wn + j * 16 + lr;
            const float bv = bq[u];
#pragma unroll
            for (int r = 0; r < 4; r++) {
                const int row = rowb + r;
                const float q = tanhf(acc[i][j][r] + bv);
                const size_t base = (size_t)row * NRS + u * 8;
                bf16x8 s8 = *(const bf16x8*)(sbuf + base);
                bf16x8 h8 = *(const bf16x8*)(hhat + base);
                bf16x8 ho;
                float hs = 0.f;
#pragma unroll
                for (int m = 0; m < 8; m++) {
                    float s = (float)s8[m];
                    float h = (float)h8[m];
                    float hn = ((1.f - s) * h + s * q) * DEC[m];
                    ho[m] = (bf16_t)hn;
                    hs += hn;
                }
                *(bf16x8*)(hhat + base) = ho;
                hnext[(size_t)row * U_ + u] = (bf16_t)hs;
            }
        }
    }
}

// dst[p][K_] = bf16(src[K_][NRS] col L), rows permuted within 64-groups.
__global__ void transpose_perm(const float* __restrict__ src, bf16_t* __restrict__ dst) {
    __shared__ float tl[32][33];
    int k0 = blockIdx.x * 32, n0 = blockIdx.y * 32;
    int tx = threadIdx.x & 31, ty = threadIdx.x >> 5;
#pragma unroll
    for (int i = 0; i < 32; i += 8)
        tl[ty + i][tx] = src[(size_t)(k0 + ty + i) * NRS + n0 + tx];
    __syncthreads();
#pragma unroll
    for (int i = 0; i < 32; i += 8) {
        int n = n0 + ty + i;
        int m = n & 7, u3v = (n >> 3) & 7;
        int p = (n & ~63) + (m & 3) * 16 + (m >> 2) * 8 + u3v;
        dst[(size_t)p * K_ + k0 + tx] = (bf16_t)tl[tx][ty + i];
    }
}

// plain transpose: dst[N][K_] = bf16(src[K_][N]^T)
__global__ void transpose_plain(const float* __restrict__ src, bf16_t* __restrict__ dst, int N) {
    __shared__ float tl[32][33];
    int k0 = blockIdx.x * 32, n0 = blockIdx.y * 32;
    int tx = threadIdx.x & 31, ty = threadIdx.x >> 5;
#pragma unroll
    for (int i = 0; i < 32; i += 8)
        tl[ty + i][tx] = src[(size_t)(k0 + ty + i) * N + n0 + tx];
    __syncthreads();
#pragma unroll
    for (int i = 0; i < 32; i += 8)
        dst[(size_t)(n0 + ty + i) * K_ + k0 + tx] = (bf16_t)tl[tx][ty + i];
}

__global__ void bias_perm(const float* __restrict__ b_r, const float* __restrict__ b_s,
                          float* __restrict__ biasP) {
    int p = blockIdx.x * 256 + threadIdx.x;  // NC
    int pr = p & 63, j = pr >> 4, lr = pr & 15;
    int L = (p & ~63) + (lr & 7) * 8 + ((lr >> 3) & 1) * 4 + j;
    biasP[p] = (L < NRS) ? b_r[L] : b_s[L - NRS];
}

// xall[t][b][f] = bf16(x[b][t][f])
__global__ void xall_build(const float* __restrict__ x, bf16_t* __restrict__ xall) {
    int idx = blockIdx.x * 256 + threadIdx.x;  // B_*T_*F_
    int b = idx >> 12;
    int rem = idx & 4095;
    int t = rem >> 8, f = rem & 255;
    xall[((size_t)t * B_ + b) * F_ + f] = (bf16_t)x[idx];
}

// One launch for all T steps: out[b,t,:] = hall[t][b][:] @ Wout + bout.
__global__ __launch_bounds__(256) void out_all(
    const bf16_t* __restrict__ hall,   // [T_][B_][U_] (slices 1..16 of alloc)
    const float* __restrict__ Wout,
    const float* __restrict__ bout,
    float* __restrict__ out)
{
    int row = blockIdx.x * 4 + (threadIdx.x >> 6);  // t*B_ + b
    int lane = threadIdx.x & 63;
    bf16x8 h8 = *(const bf16x8*)(hall + (size_t)row * U_ + lane * 8);
    float p0 = 0, p1 = 0, p2 = 0;
#pragma unroll
    for (int k = 0; k < 8; k++) {
        float h = (float)h8[k];
        int u = lane * 8 + k;
        p0 += h * Wout[u * 3 + 0];
        p1 += h * Wout[u * 3 + 1];
        p2 += h * Wout[u * 3 + 2];
    }
    for (int off = 32; off; off >>= 1) {
        p0 += __shfl_down(p0, off, 64);
        p1 += __shfl_down(p1, off, 64);
        p2 += __shfl_down(p2, off, 64);
    }
    if (lane == 0) {
        int t = row >> 12, b = row & (B_ - 1);
        size_t o = ((size_t)b * T_ + t) * 3;
        out[o + 0] = p0 + bout[0];
        out[o + 1] = p1 + bout[1];
        out[o + 2] = p2 + bout[2];
    }
}

extern "C" void kernel_launch(void* const* d_in, const int* in_sizes, int n_in,
                              void* d_out, int out_size, void* d_ws, size_t ws_size,
                              hipStream_t stream) {
    const float* x   = (const float*)d_in[0];
    const float* W_r = (const float*)d_in[1];
    const float* b_r = (const float*)d_in[2];
    const float* W_q = (const float*)d_in[3];
    const float* b_q = (const float*)d_in[4];
    const float* W_s = (const float*)d_in[5];
    const float* b_s = (const float*)d_in[6];
    const float* W_o = (const float*)d_in[7];
    const float* b_o = (const float*)d_in[8];
    float* out = (float*)d_out;

    char* ws = (char*)d_ws;
    bf16_t* hhat  = (bf16_t*)ws; ws += (size_t)B_ * NRS * 2;         // 32 MB
    bf16_t* sbuf  = (bf16_t*)ws; ws += (size_t)B_ * NRS * 2;         // 32 MB
    bf16_t* xall  = (bf16_t*)ws; ws += (size_t)B_ * T_ * F_ * 2;     // 32 MB
    bf16_t* hall  = (bf16_t*)ws; ws += (size_t)(T_ + 1) * B_ * U_ * 2; // 68 MB
    bf16_t* rh    = (bf16_t*)ws; ws += (size_t)B_ * U_ * 2;          // 4 MB
    bf16_t* WrsT  = (bf16_t*)ws; ws += (size_t)NC * K_ * 2;          // 12 MB
    bf16_t* WqT   = (bf16_t*)ws; ws += (size_t)U_ * K_ * 2;          // 0.75 MB
    float*  biasP = (float*)ws;  ws += (size_t)NC * 4;               // 32 KB

    hipMemsetAsync(hhat, 0, (size_t)B_ * NRS * 2, stream);
    hipMemsetAsync(hall, 0, (size_t)B_ * U_ * 2, stream);  // slice 0 = h(-1)=0
    xall_build<<<B_ * T_ * F_ / 256, 256, 0, stream>>>(x, xall);
    transpose_perm<<<dim3(K_ / 32, NRS / 32), 256, 0, stream>>>(W_r, WrsT);
    transpose_perm<<<dim3(K_ / 32, NRS / 32), 256, 0, stream>>>(W_s, WrsT + (size_t)NRS * K_);
    transpose_plain<<<dim3(K_ / 32, U_ / 32), 256, 0, stream>>>(W_q, WqT, U_);
    bias_perm<<<NC / 256, 256, 0, stream>>>(b_r, b_s, biasP);

    for (int t = 0; t < T_; t++) {
        const bf16_t* xt = xall + (size_t)t * B_ * F_;
        const bf16_t* hp = hall + (size_t)t * B_ * U_;        // h(t-1)
        bf16_t*       hn = hall + (size_t)(t + 1) * B_ * U_;  // h(t)
        gemm_rs_p2<<<dim3(16, 32), 512, 0, stream>>>(xt, hp, WrsT, biasP, hhat, rh, sbuf);
        gemm_q_up<<<dim3(64, 8), 256, 0, stream>>>(xt, rh, WqT, b_q, sbuf, hhat, hn);
    }
    out_all<<<B_ * T_ / 4, 256, 0, stream>>>(hall + (size_t)B_ * U_, W_o, b_o, out);
}

// Round 4
// 1792.182 us; speedup vs baseline: 1.0060x; 1.0060x over previous
//
#include <hip/hip_runtime.h>
#include <hip/hip_bf16.h>
#include <math.h>

#define B_   4096
#define T_   16
#define F_   256
#define U_   512
#define M_   8
#define K_   768    // F+U
#define NRS  4096   // U*M
#define NC   8192   // combined R|S output cols
#define LNT  1.1512925f  // 0.5*ln(10)

typedef __bf16 bf16_t;
typedef bf16_t bf16x8 __attribute__((ext_vector_type(8)));
typedef bf16_t bf16x4 __attribute__((ext_vector_type(4)));
typedef float  f32x4  __attribute__((ext_vector_type(4)));

__device__ inline void gl_lds16(const void* g, void* lds) {
    __builtin_amdgcn_global_load_lds(
        (const __attribute__((address_space(1))) unsigned int*)g,
        (__attribute__((address_space(3))) unsigned int*)lds, 16, 0, 0);
}

#define VMCNT(n) asm volatile("s_waitcnt vmcnt(" #n ")" ::: "memory")
#define LGKM0()  asm volatile("s_waitcnt lgkmcnt(0)" ::: "memory")
#define BAR()    __builtin_amdgcn_s_barrier()

// ---------------------------------------------------------------------------
// Pre-tiled operand format ("slot" = 256 rows x 32 cols bf16 = 16 KB):
//   elem offset r*32 + q*8 + e holds SOURCE column (q ^ ((r>>1)&3))*8 + e
// i.e. the T2 inverse-swizzle is baked into the DATA. Staging is then a pure
// linear copy (each gl_lds16: 64 lanes x 16B contiguous = one 1KB VMEM
// transaction — no scattered sectors), and ds_read applies the same XOR key.
// ---------------------------------------------------------------------------
__device__ inline void stage_slot(const bf16_t* src, bf16_t* dst, int tid) {
    gl_lds16(src + tid * 8,        (char*)dst + tid * 16);          // 8 KB
    gl_lds16(src + tid * 8 + 4096, (char*)dst + tid * 16 + 8192);   // 8 KB
}

__device__ inline void ds_read4(const bf16_t* base, bf16x8 (&v)[4]) {
    v[0] = *(const bf16x8*)(base);
    v[1] = *(const bf16x8*)(base + 512);
    v[2] = *(const bf16x8*)(base + 1024);
    v[3] = *(const bf16x8*)(base + 1536);
}

template <int H>
__device__ inline void mfma16(f32x4 (&acc)[8][4], const bf16x8 (&a)[4],
                              const bf16x8 (&b)[4]) {
    __builtin_amdgcn_s_setprio(1);
#pragma unroll
    for (int i = 0; i < 4; ++i)
#pragma unroll
        for (int j = 0; j < 4; ++j)
            acc[H * 4 + i][j] = __builtin_amdgcn_mfma_f32_16x16x32_bf16(
                a[i], b[j], acc[H * 4 + i][j], 0, 0, 0);
    __builtin_amdgcn_s_setprio(0);
}

// ---------------------------------------------------------------------------
// Combined R|S GEMM, 256x256 tile, 8 waves (2Mx4N), per-wave 128x64.
// Schedule = R3's (1 barrier/K-32 tile, parity dbuf, 64 KiB LDS, 2 blk/CU).
// ONLY change vs R3: all operands pre-tiled -> staging is linear 1KB/inst.
// A slots 0..7 from xtile (this step), 8..23 from htile (written tiled by
// gemm_q of the previous step). B slots from Btile (built once).
// ---------------------------------------------------------------------------
__global__ __launch_bounds__(512, 2) void gemm_rs_tp(
    const bf16_t* __restrict__ xt_t,   // xtiles slice t: [16 mp][8 s][8192]
    const bf16_t* __restrict__ ht,     // htile: [16 mp][16 s][8192]
    const bf16_t* __restrict__ Bt,     // Btile: [32 np][24 s][8192]
    const float*  __restrict__ biasP,  // [NC] (perm)
    const bf16_t* __restrict__ hhat,   // [B_][NRS]
    bf16_t* __restrict__ rh,           // [B_][U_]
    bf16_t* __restrict__ sbuf)         // [B_][NRS]
{
    __shared__ __attribute__((aligned(16))) bf16_t Asl[2][8192];   // 32 KiB
    __shared__ __attribute__((aligned(16))) bf16_t Bsl[2][8192];   // 32 KiB

    const int tid  = threadIdx.x;
    const int lane = tid & 63;
    const int wave = tid >> 6;

    // Bijective XCD swizzle: XCD c owns a 4m x 16n rectangle (verified R2:
    // FETCH 118->53.5 MB, near-minimal).
    const int lin = blockIdx.y * 16 + blockIdx.x;
    const int xcd = lin & 7, q = lin >> 3;
    const int m0 = ((xcd >> 1) * 4 + (q & 3)) * 256;
    const int n0 = ((xcd & 1) * 16 + (q >> 2)) * 256;
    const int mp = m0 >> 8, np = n0 >> 8;

    const int wm = wave >> 2;          // 0..1
    const int wn = wave & 3;           // 0..3
    const int lr = lane & 15;
    const int kq = lane >> 4;
    // read-side XOR: 16B-chunk = kq ^ ((row>>1)&3); rows are 16a+lr so the
    // key reduces to (lr>>1)&3 (lane-uniform across fragments).
    const int cr = (kq ^ ((lr >> 1) & 3)) * 8;

    const int aoff0 = (wm * 128 + lr) * 32 + cr;        // M-half 0
    const int aoff1 = (wm * 128 + 64 + lr) * 32 + cr;   // M-half 1
    const int boff  = (wn * 64 + lr) * 32 + cr;

    f32x4 acc[8][4] = {};
    bf16x8 a[4], b[4];

#define ASRC(S) ((S) < 8 ? xt_t + (size_t)(mp * 8 + (S)) * 8192               \
                         : ht   + (size_t)(mp * 16 + (S) - 8) * 8192)
#define BSRC(S) (Bt + (size_t)(np * 24 + (S)) * 8192)

    // Prologue: slot 0 staged, drained.
    stage_slot(ASRC(0), &Asl[0][0], tid);
    stage_slot(BSRC(0), &Bsl[0][0], tid);
    VMCNT(0);
    BAR();

#define TILE(T, SFLAG)                                                        \
  {                                                                           \
    const int p_ = (T) & 1, pn_ = p_ ^ 1;                                     \
    if (SFLAG) {                                                              \
      stage_slot(ASRC((T) + 1), &Asl[pn_][0], tid);                           \
      stage_slot(BSRC((T) + 1), &Bsl[pn_][0], tid);                           \
    }                                                                         \
    ds_read4(&Asl[p_][0] + aoff0, a);                                         \
    ds_read4(&Bsl[p_][0] + boff, b);                                          \
    LGKM0();                                                                  \
    mfma16<0>(acc, a, b);                                                     \
    ds_read4(&Asl[p_][0] + aoff1, a);                                         \
    LGKM0();                                                                  \
    mfma16<1>(acc, a, b);                                                     \
    VMCNT(0);                                                                 \
    BAR();                                                                    \
  }

    for (int tt = 0; tt < 22; tt += 2) { TILE(tt, 1); TILE(tt + 1, 1); }
    TILE(22, 1);
    TILE(23, 0);
#undef TILE
#undef ASRC
#undef BSRC

    // ------------------- fused softmax epilogue (unchanged math) -----------
    const int nb  = n0 + wn * 64;
    const int u3  = lane & 7;
    const int m0v = ((lane >> 3) & 1) * 4;
    const bool is_r = nb < NRS;

    float bj[4];
#pragma unroll
    for (int j = 0; j < 4; ++j) bj[j] = biasP[nb + j * 16 + lr];

#pragma unroll
    for (int mi = 0; mi < 8; ++mi) {
        const int rowb = m0 + wm * 128 + mi * 16 + kq * 4;
#pragma unroll
        for (int r = 0; r < 4; ++r) {
            const int row = rowb + r;
            float e[4], sum = 0.f;
#pragma unroll
            for (int j = 0; j < 4; ++j) {
                float v = acc[mi][j][r] + bj[j];
                float d = v - (float)(m0v + j) * LNT;
                e[j] = __expf(-d * d);
                sum += e[j];
            }
            sum += __shfl_xor(sum, 8, 64);
            const float inv = 1.0f / sum;
            if (is_r) {
                bf16x4 h4 = *(const bf16x4*)(hhat + (size_t)row * NRS + nb + u3 * 8 + m0v);
                float rhv = 0.f;
#pragma unroll
                for (int j = 0; j < 4; ++j) rhv += e[j] * inv * (float)h4[j];
                rhv += __shfl_xor(rhv, 8, 64);
                if ((lane & 8) == 0)
                    rh[(size_t)row * U_ + (nb >> 3) + u3] = (bf16_t)rhv;
            } else {
                bf16x4 pv;
#pragma unroll
                for (int j = 0; j < 4; ++j) pv[j] = (bf16_t)(e[j] * inv);
                *(bf16x4*)(sbuf + (size_t)row * NRS + (nb - NRS) + u3 * 8 + m0v) = pv;
            }
        }
    }
}

// ---------------------------------------------------------------------------
// q GEMM (64x64 tiles, grid 64x8=512) + fused state update. A x-part comes
// from xtiles (contiguous 4KB slot copies, swizzled format); rh part staged
// with the inverse-swizzled source column (same LDS format); A reads un-XOR.
// B (WqT) stays linear staged + linear read. Epilogue additionally writes the
// TILED h (htile) consumed by the next step's gemm_rs_tp.
// ---------------------------------------------------------------------------
__global__ __launch_bounds__(256) void gemm_q_up(
    const bf16_t* __restrict__ xt_t,   // xtiles slice t
    const bf16_t* __restrict__ rh,     // [B_][U_]
    const bf16_t* __restrict__ Bq,     // WqT [U_][K_]
    const float*  __restrict__ bq,
    const bf16_t* __restrict__ sbuf,
    bf16_t* __restrict__ hhat,
    bf16_t* __restrict__ hnext,        // hall slice t+1: [B_][U_]
    bf16_t* __restrict__ htile)        // [16 mp][16 s][8192]
{
    __shared__ __attribute__((aligned(16))) bf16_t Al[2][64 * 32];
    __shared__ __attribute__((aligned(16))) bf16_t Bl[2][64 * 32];

    const int tid  = threadIdx.x;
    const int lane = tid & 63;
    const int wave = tid >> 6;
    const int m0 = blockIdx.x * 64;
    const int n0 = blockIdx.y * 64;
    const int wm = (wave & 1) * 32;
    const int wn = (wave >> 1) * 32;
    const int lr = lane & 15;
    const int kq = lane >> 4;
    const int crq = (kq ^ ((lr >> 1) & 3)) * 8;   // A un-XOR read

    f32x4 acc[2][2] = {};

    const int rA  = tid >> 2;
    const int kc  = (tid & 3) * 8;                        // linear (B)
    const int kcs = ((tid & 3) ^ ((tid >> 3) & 3)) * 8;   // inv-swz (A rh)

    for (int kk = 0; kk < K_; kk += 64) {
        __syncthreads();
        if (kk < F_) {
            const bf16_t* s0p = xt_t + (size_t)((m0 >> 8) * 8 + (kk >> 5)) * 8192
                                     + (size_t)(m0 & 255) * 32;
            gl_lds16(s0p + tid * 8,        (char*)&Al[0][0] + tid * 16);
            gl_lds16(s0p + 8192 + tid * 8, (char*)&Al[1][0] + tid * 16);
        } else {
            const int cb = kk - F_;
            gl_lds16(rh + (size_t)(m0 + rA) * U_ + cb + kcs,      (char*)&Al[0][0] + tid * 16);
            gl_lds16(rh + (size_t)(m0 + rA) * U_ + cb + 32 + kcs, (char*)&Al[1][0] + tid * 16);
        }
        gl_lds16(Bq + (size_t)(n0 + rA) * K_ + kk + kc,      (char*)&Bl[0][0] + tid * 16);
        gl_lds16(Bq + (size_t)(n0 + rA) * K_ + kk + 32 + kc, (char*)&Bl[1][0] + tid * 16);
        __syncthreads();

#pragma unroll
        for (int s = 0; s < 2; s++) {
            bf16x8 af[2], bfr[2];
#pragma unroll
            for (int i = 0; i < 2; i++)
                af[i] = *(const bf16x8*)(&Al[s][0] + (wm + i * 16 + lr) * 32 + crq);
#pragma unroll
            for (int i = 0; i < 2; i++)
                bfr[i] = *(const bf16x8*)(&Bl[s][0] + (wn + i * 16 + lr) * 32 + kq * 8);
#pragma unroll
            for (int i = 0; i < 2; i++)
#pragma unroll
                for (int j = 0; j < 2; j++)
                    acc[i][j] = __builtin_amdgcn_mfma_f32_16x16x32_bf16(
                        af[i], bfr[j], acc[i][j], 0, 0, 0);
        }
    }

    const float DEC[8] = {0.0f, 0.9658531f, 0.9827783f, 0.9884856f,
                          0.9913518f, 0.9930754f, 0.9942261f, 0.9950489f};

#pragma unroll
    for (int i = 0; i < 2; i++) {
        const int rowb = m0 + wm + i * 16 + kq * 4;
#pragma unroll
        for (int j = 0; j < 2; j++) {
            const int u = n0 + wn + j * 16 + lr;
            const float bv = bq[u];
            const int us = u >> 5, uc = u & 31;
#pragma unroll
            for (int r = 0; r < 4; r++) {
                const int row = rowb + r;
                const float q = tanhf(acc[i][j][r] + bv);
                const size_t base = (size_t)row * NRS + u * 8;
                bf16x8 s8 = *(const bf16x8*)(sbuf + base);
                bf16x8 h8 = *(const bf16x8*)(hhat + base);
                bf16x8 ho;
                float hs = 0.f;
#pragma unroll
                for (int m = 0; m < 8; m++) {
                    float s = (float)s8[m];
                    float h = (float)h8[m];
                    float hn = ((1.f - s) * h + s * q) * DEC[m];
                    ho[m] = (bf16_t)hn;
                    hs += hn;
                }
                *(bf16x8*)(hhat + base) = ho;
                hnext[(size_t)row * U_ + u] = (bf16_t)hs;
                const int rl = row & 255;
                htile[(size_t)((row >> 8) * 16 + us) * 8192 + rl * 32
                      + (((uc >> 3) ^ ((rl >> 1) & 3)) * 8) + (uc & 7)] = (bf16_t)hs;
            }
        }
    }
}

// dst[p][K_] = bf16(src[K_][NRS] col L), rows permuted within 64-groups.
__global__ void transpose_perm(const float* __restrict__ src, bf16_t* __restrict__ dst) {
    __shared__ float tl[32][33];
    int k0 = blockIdx.x * 32, n0 = blockIdx.y * 32;
    int tx = threadIdx.x & 31, ty = threadIdx.x >> 5;
#pragma unroll
    for (int i = 0; i < 32; i += 8)
        tl[ty + i][tx] = src[(size_t)(k0 + ty + i) * NRS + n0 + tx];
    __syncthreads();
#pragma unroll
    for (int i = 0; i < 32; i += 8) {
        int n = n0 + ty + i;
        int m = n & 7, u3v = (n >> 3) & 7;
        int p = (n & ~63) + (m & 3) * 16 + (m >> 2) * 8 + u3v;
        dst[(size_t)p * K_ + k0 + tx] = (bf16_t)tl[tx][ty + i];
    }
}

// Btile[np][s][8192] from WrsT rows (perm already applied by transpose_perm).
__global__ void btile_build(const bf16_t* __restrict__ WrsT, bf16_t* __restrict__ Bt) {
    int n = blockIdx.x / 3;
    int k = (blockIdx.x % 3) * 256 + threadIdx.x;
    int p = n >> 8, r = n & 255, s = k >> 5, c = k & 31;
    Bt[(size_t)(p * 24 + s) * 8192 + r * 32
       + (((c >> 3) ^ ((r >> 1) & 3)) * 8) + (c & 7)] = WrsT[(size_t)n * K_ + k];
}

// plain transpose: dst[N][K_] = bf16(src[K_][N]^T)
__global__ void transpose_plain(const float* __restrict__ src, bf16_t* __restrict__ dst, int N) {
    __shared__ float tl[32][33];
    int k0 = blockIdx.x * 32, n0 = blockIdx.y * 32;
    int tx = threadIdx.x & 31, ty = threadIdx.x >> 5;
#pragma unroll
    for (int i = 0; i < 32; i += 8)
        tl[ty + i][tx] = src[(size_t)(k0 + ty + i) * N + n0 + tx];
    __syncthreads();
#pragma unroll
    for (int i = 0; i < 32; i += 8)
        dst[(size_t)(n0 + ty + i) * K_ + k0 + tx] = (bf16_t)tl[tx][ty + i];
}

__global__ void bias_perm(const float* __restrict__ b_r, const float* __restrict__ b_s,
                          float* __restrict__ biasP) {
    int p = blockIdx.x * 256 + threadIdx.x;  // NC
    int pr = p & 63, j = pr >> 4, lr = pr & 15;
    int L = (p & ~63) + (lr & 7) * 8 + ((lr >> 3) & 1) * 4 + j;
    biasP[p] = (L < NRS) ? b_r[L] : b_s[L - NRS];
}

// xtiles[t][mp][s][8192] = tiled+inv-swizzled bf16(x[b][t][f])
__global__ void xtile_build(const float* __restrict__ x, bf16_t* __restrict__ xt) {
    int idx = blockIdx.x * 256 + threadIdx.x;  // B_*T_*F_
    int b = idx >> 12;
    int rem = idx & 4095;
    int t = rem >> 8, f = rem & 255;
    int mp = b >> 8, r = b & 255, s = f >> 5, c = f & 31;
    xt[((size_t)(t * 16 + mp) * 8 + s) * 8192 + r * 32
       + (((c >> 3) ^ ((r >> 1) & 3)) * 8) + (c & 7)] = (bf16_t)x[idx];
}

// One launch for all T steps: out[b,t,:] = hall[t][b][:] @ Wout + bout.
__global__ __launch_bounds__(256) void out_all(
    const bf16_t* __restrict__ hall,   // [T_][B_][U_] (slices 1..16 of alloc)
    const float* __restrict__ Wout,
    const float* __restrict__ bout,
    float* __restrict__ out)
{
    int row = blockIdx.x * 4 + (threadIdx.x >> 6);  // t*B_ + b
    int lane = threadIdx.x & 63;
    bf16x8 h8 = *(const bf16x8*)(hall + (size_t)row * U_ + lane * 8);
    float p0 = 0, p1 = 0, p2 = 0;
#pragma unroll
    for (int k = 0; k < 8; k++) {
        float h = (float)h8[k];
        int u = lane * 8 + k;
        p0 += h * Wout[u * 3 + 0];
        p1 += h * Wout[u * 3 + 1];
        p2 += h * Wout[u * 3 + 2];
    }
    for (int off = 32; off; off >>= 1) {
        p0 += __shfl_down(p0, off, 64);
        p1 += __shfl_down(p1, off, 64);
        p2 += __shfl_down(p2, off, 64);
    }
    if (lane == 0) {
        int t = row >> 12, b = row & (B_ - 1);
        size_t o = ((size_t)b * T_ + t) * 3;
        out[o + 0] = p0 + bout[0];
        out[o + 1] = p1 + bout[1];
        out[o + 2] = p2 + bout[2];
    }
}

extern "C" void kernel_launch(void* const* d_in, const int* in_sizes, int n_in,
                              void* d_out, int out_size, void* d_ws, size_t ws_size,
                              hipStream_t stream) {
    const float* x   = (const float*)d_in[0];
    const float* W_r = (const float*)d_in[1];
    const float* b_r = (const float*)d_in[2];
    const float* W_q = (const float*)d_in[3];
    const float* b_q = (const float*)d_in[4];
    const float* W_s = (const float*)d_in[5];
    const float* b_s = (const float*)d_in[6];
    const float* W_o = (const float*)d_in[7];
    const float* b_o = (const float*)d_in[8];
    float* out = (float*)d_out;

    char* ws = (char*)d_ws;
    bf16_t* hhat  = (bf16_t*)ws; ws += (size_t)B_ * NRS * 2;           // 33.5 MB
    bf16_t* sbuf  = (bf16_t*)ws; ws += (size_t)B_ * NRS * 2;           // 33.5 MB
    bf16_t* xtile = (bf16_t*)ws; ws += (size_t)B_ * T_ * F_ * 2;       // 33.5 MB
    bf16_t* hall  = (bf16_t*)ws; ws += (size_t)(T_ + 1) * B_ * U_ * 2; // 71 MB
    bf16_t* rh    = (bf16_t*)ws; ws += (size_t)B_ * U_ * 2;            // 4.2 MB
    bf16_t* WrsT  = (bf16_t*)ws; ws += (size_t)NC * K_ * 2;            // 12.6 MB
    bf16_t* Btile = (bf16_t*)ws; ws += (size_t)NC * K_ * 2;            // 12.6 MB
    bf16_t* htile = (bf16_t*)ws; ws += (size_t)B_ * U_ * 2;            // 4.2 MB
    bf16_t* WqT   = (bf16_t*)ws; ws += (size_t)U_ * K_ * 2;            // 0.79 MB
    float*  biasP = (float*)ws;  ws += (size_t)NC * 4;                 // 32 KB

    hipMemsetAsync(hhat, 0, (size_t)B_ * NRS * 2, stream);
    hipMemsetAsync(htile, 0, (size_t)B_ * U_ * 2, stream);  // h(-1)=0 tiled
    xtile_build<<<B_ * T_ * F_ / 256, 256, 0, stream>>>(x, xtile);
    transpose_perm<<<dim3(K_ / 32, NRS / 32), 256, 0, stream>>>(W_r, WrsT);
    transpose_perm<<<dim3(K_ / 32, NRS / 32), 256, 0, stream>>>(W_s, WrsT + (size_t)NRS * K_);
    btile_build<<<NC * 3, 256, 0, stream>>>(WrsT, Btile);
    transpose_plain<<<dim3(K_ / 32, U_ / 32), 256, 0, stream>>>(W_q, WqT, U_);
    bias_perm<<<NC / 256, 256, 0, stream>>>(b_r, b_s, biasP);

    for (int t = 0; t < T_; t++) {
        const bf16_t* xt_t = xtile + (size_t)t * 16 * 8 * 8192;
        bf16_t*       hn   = hall + (size_t)(t + 1) * B_ * U_;  // h(t)
        gemm_rs_tp<<<dim3(16, 32), 512, 0, stream>>>(xt_t, htile, Btile, biasP, hhat, rh, sbuf);
        gemm_q_up<<<dim3(64, 8), 256, 0, stream>>>(xt_t, rh, WqT, b_q, sbuf, hhat, hn, htile);
    }
    out_all<<<B_ * T_ / 4, 256, 0, stream>>>(hall + (size_t)B_ * U_, W_o, b_o, out);
}